// Round 11
// baseline (116.788 us; speedup 1.0000x reference)
//
#include <hip/hip_runtime.h>
#include <hip/hip_bf16.h>
#include <stdint.h>

#define Bz 2
#define Sz 2048
#define Dz 768
#define Hz 12
#define DHz 64
#define Mz (Bz*Sz)    // 4096
#define NQT 32        // 64-row q-tiles per (b,h)

typedef __attribute__((ext_vector_type(4))) float f32x4;
typedef __attribute__((ext_vector_type(8))) short bf16x8;
typedef unsigned short u16;
typedef __attribute__((ext_vector_type(8))) unsigned short u16x8;

__device__ __forceinline__ u16 f2bf(float f) {
  union { float f; uint32_t u; } c; c.f = f;
  uint32_t u = c.u;
  return (u16)((u + 0x7fffu + ((u >> 16) & 1u)) >> 16);
}

#define GLL16(gsrc, ldst) \
  __builtin_amdgcn_global_load_lds((const __attribute__((address_space(1))) void*)(gsrc), \
                                   (__attribute__((address_space(3))) void*)(ldst), 16, 0, 0)

__device__ __forceinline__ f32x4 mfma16(bf16x8 a, bf16x8 b, f32x4 c) {
  return __builtin_amdgcn_mfma_f32_16x16x32_bf16(a, b, c, 0, 0, 0);
}

// ---------------- pre-pass: fp32 -> bf16 (q,k,v fused in one launch) ----------------
__global__ void cvt3_kernel(const float* __restrict__ qa, const float* __restrict__ ka,
                            const float* __restrict__ va,
                            u16* __restrict__ qo, u16* __restrict__ ko, u16* __restrict__ vo,
                            int n8) {
  int i = blockIdx.x * blockDim.x + threadIdx.x;
  if (i >= n8) return;
  int z = blockIdx.y;
  const float* src = (z == 0) ? qa : (z == 1) ? ka : va;
  u16* dst = (z == 0) ? qo : (z == 1) ? ko : vo;
  const float4* s4 = (const float4*)src;
  float4 a = s4[(size_t)i * 2];
  float4 b = s4[(size_t)i * 2 + 1];
  u16x8 o;
  o[0] = f2bf(a.x); o[1] = f2bf(a.y); o[2] = f2bf(a.z); o[3] = f2bf(a.w);
  o[4] = f2bf(b.x); o[5] = f2bf(b.y); o[6] = f2bf(b.z); o[7] = f2bf(b.w);
  *(u16x8*)(dst + (size_t)i * 8) = o;
}

// ---------------- pre-pass: W [K][N] fp32 -> Wt [N][K] bf16 (4 weights fused) ----------------
__global__ void wtrans4_kernel(const float* __restrict__ W0, const float* __restrict__ W1,
                               const float* __restrict__ W2, const float* __restrict__ W3,
                               u16* __restrict__ T0, u16* __restrict__ T1,
                               u16* __restrict__ T2, u16* __restrict__ T3) {
  __shared__ float tile[32][33];
  int z = blockIdx.z;
  const float* W = (z == 0) ? W0 : (z == 1) ? W1 : (z == 2) ? W2 : W3;
  u16* Wt = (z == 0) ? T0 : (z == 1) ? T1 : (z == 2) ? T2 : T3;
  int bx = blockIdx.x * 32, by = blockIdx.y * 32;
  int tx = threadIdx.x & 31, ty = threadIdx.x >> 5;   // 256 threads: ty 0..7
#pragma unroll
  for (int i = 0; i < 32; i += 8)
    tile[ty + i][tx] = W[(size_t)(by + ty + i) * Dz + bx + tx];
  __syncthreads();
#pragma unroll
  for (int i = 0; i < 32; i += 8)
    Wt[(size_t)(bx + ty + i) * Dz + by + tx] = f2bf(tile[tx][ty + i]);
}

// ---------------- GEMM core (R10, proven): triple-buffer, 1 barrier, counted vmcnt ----------------
__device__ __forceinline__ void gemm_core(
    const u16* __restrict__ A, const u16* __restrict__ Wt,
    const float* __restrict__ bias, void* __restrict__ out, int mode, float oscale,
    u16 (*As)[128 * 32], u16 (*Bs)[128 * 32])
{
  const int tid = threadIdx.x;
  const int wid = tid >> 6, lane = tid & 63;
  const int wm = wid >> 1, wn = wid & 1;
  const int m0 = blockIdx.x * 128, n0 = blockIdx.y * 128;
  const int fq = lane >> 4, fr = lane & 15;

  int aoff[2];
#pragma unroll
  for (int c = 0; c < 2; ++c) {
    int off  = (wid * 2 + c) * 1024 + lane * 16;
    int row  = off >> 6;
    int colb = (off & 63) ^ (((row >> 1) & 3) << 4);
    aoff[c]  = row * Dz + (colb >> 1);
  }

  int raddr[4], rbaddr[4];
#pragma unroll
  for (int f = 0; f < 4; ++f) {
    int rowA = wm * 64 + f * 16 + fr;
    raddr[f]  = rowA * 64 + ((fq * 16) ^ (((rowA >> 1) & 3) << 4));
    int rowB = wn * 64 + f * 16 + fr;
    rbaddr[f] = rowB * 64 + ((fq * 16) ^ (((rowB >> 1) & 3) << 4));
  }

  f32x4 acc[4][4];
  const f32x4 zero = {0.f, 0.f, 0.f, 0.f};
#pragma unroll
  for (int i = 0; i < 4; ++i)
#pragma unroll
    for (int j = 0; j < 4; ++j) acc[i][j] = zero;

  const u16* Abase = A + (size_t)m0 * Dz;
  const u16* Bbase = Wt + (size_t)n0 * Dz;

  const int NKT = Dz / 32;   // 24
#pragma unroll
  for (int c = 0; c < 2; ++c) {
    GLL16(Abase + aoff[c], (char*)As[0] + (wid * 2 + c) * 1024);
    GLL16(Bbase + aoff[c], (char*)Bs[0] + (wid * 2 + c) * 1024);
  }
  int cur = 0;

  for (int kt = 0; kt < NKT; ++kt) {
    int nx = cur + 1; if (nx == 3) nx = 0;
    if (kt + 1 < NKT) {
      int ke = (kt + 1) * 32;
#pragma unroll
      for (int c = 0; c < 2; ++c) {
        GLL16(Abase + ke + aoff[c], (char*)As[nx] + (wid * 2 + c) * 1024);
        GLL16(Bbase + ke + aoff[c], (char*)Bs[nx] + (wid * 2 + c) * 1024);
      }
      asm volatile("s_waitcnt vmcnt(4)" ::: "memory");
    } else {
      asm volatile("s_waitcnt vmcnt(0)" ::: "memory");
    }
    __builtin_amdgcn_s_barrier();
    __builtin_amdgcn_sched_barrier(0);

    bf16x8 af[4], bf[4];
#pragma unroll
    for (int f = 0; f < 4; ++f) {
      af[f] = *(const bf16x8*)((const char*)As[cur] + raddr[f]);
      bf[f] = *(const bf16x8*)((const char*)Bs[cur] + rbaddr[f]);
    }
    __builtin_amdgcn_s_setprio(1);
#pragma unroll
    for (int i = 0; i < 4; ++i)
#pragma unroll
      for (int j = 0; j < 4; ++j)
        acc[i][j] = mfma16(af[i], bf[j], acc[i][j]);
    __builtin_amdgcn_s_setprio(0);
    cur = nx;
  }

  if (mode == 2) {
    float* O = (float*)out;
#pragma unroll
    for (int i = 0; i < 4; ++i) {
      int grow = m0 + wm * 64 + i * 16 + fq * 4;
#pragma unroll
      for (int j = 0; j < 4; ++j) {
        int gcol = n0 + wn * 64 + j * 16 + fr;
        float bv = bias[gcol];
#pragma unroll
        for (int r = 0; r < 4; ++r)
          O[(size_t)(grow + r) * Dz + gcol] = acc[i][j][r] + bv;
      }
    }
  } else {
    u16* O = (u16*)out;
#pragma unroll
    for (int i = 0; i < 4; ++i) {
      int grow = m0 + wm * 64 + i * 16 + fq * 4;
#pragma unroll
      for (int j = 0; j < 4; ++j) {
        int gcol = n0 + wn * 64 + j * 16 + fr;
        float bv = bias[gcol];
        int h = gcol >> 6, dh = gcol & 63;
#pragma unroll
        for (int r = 0; r < 4; ++r) {
          int t = grow + r;
          int b = t >> 11, s = t & 2047;
          float v = (acc[i][j][r] + bv) * oscale;
          if (mode == 0)
            O[((size_t)(b * Hz + h) * Sz + s) * DHz + dh] = f2bf(v);
          else
            O[((size_t)(b * Hz + h) * DHz + dh) * Sz + s] = f2bf(v);
        }
      }
    }
  }
}

// Q is pre-scaled by 1/sqrt(DH) * log2(e) so attention can use raw v_exp_f32 (exp2)
#define QSCALE 0.1803368801111404f   // 0.125 * 1.4426950408889634

__global__ __launch_bounds__(256, 2) void gemm_qkv(
    const u16* __restrict__ qb, const u16* __restrict__ kb, const u16* __restrict__ vb,
    const u16* __restrict__ Wqt, const u16* __restrict__ Wkt, const u16* __restrict__ Wvt,
    const float* __restrict__ bq, const float* __restrict__ bk, const float* __restrict__ bv,
    u16* __restrict__ Qh, u16* __restrict__ Kh, u16* __restrict__ Vt)
{
  __shared__ u16 As[3][128 * 32];
  __shared__ u16 Bs[3][128 * 32];
  const u16* A; const u16* W; const float* bias; u16* out; int mode; float osc;
  if (blockIdx.z == 0)      { A = qb; W = Wqt; bias = bq; out = Qh; mode = 0; osc = QSCALE; }
  else if (blockIdx.z == 1) { A = kb; W = Wkt; bias = bk; out = Kh; mode = 0; osc = 1.f; }
  else                      { A = vb; W = Wvt; bias = bv; out = Vt; mode = 1; osc = 1.f; }
  gemm_core(A, W, bias, out, mode, osc, As, Bs);
}

__global__ __launch_bounds__(256, 2) void gemm_out_k(
    const u16* __restrict__ ctx, const u16* __restrict__ Wot,
    const float* __restrict__ bo, float* __restrict__ out)
{
  __shared__ u16 As[3][128 * 32];
  __shared__ u16 Bs[3][128 * 32];
  gemm_core(ctx, Wot, bo, (void*)out, 2, 1.f, As, Bs);
}

// ---------------- flash attention, causal, DUAL-STREAM 64-ROW TILES ----------------
// grid (B*H, NQT) = (24, 32), 128-thread blocks (2 waves). bq = 31 - y (LPT).
// Block = one 64-row q-tile; each wave owns 32 rows = 2 ALWAYS-ACTIVE 16-row
// groups processed as interleavable streams in one basic block per iteration:
//   loads -> QK(g0)+QK(g1) [setprio cluster] -> masks -> softmax(g0)||softmax(g1)
//   -> PV(g0)+PV(g1) [setprio cluster].
// Staging: R8-proven form (stage after __syncthreads, double buffer).
__device__ __forceinline__ void stage_kv(const u16* __restrict__ Kg, const u16* __restrict__ Vg,
                                         int kt, u16* Ks, u16* Vs, int wid, int lane) {
#pragma unroll
  for (int c = 0; c < 4; ++c) {
    int off  = (wid * 4 + c) * 1024 + lane * 16;
    int row  = off >> 7;                       // 128B rows (64 bf16)
    int colb = (off & 127) ^ ((row & 7) << 4); // XOR swizzle bits 4-6
    GLL16(Kg + ((size_t)(kt * 64 + row)) * DHz + (colb >> 1), (char*)Ks + (wid * 4 + c) * 1024);
    GLL16(Vg + (size_t)row * Sz + kt * 64 + (colb >> 1),      (char*)Vs + (wid * 4 + c) * 1024);
  }
}

__global__ __launch_bounds__(128, 2) void attn_kernel(
    const u16* __restrict__ Qh, const u16* __restrict__ Kh,
    const u16* __restrict__ Vt, u16* __restrict__ ctx)
{
  __shared__ u16 Ks[2][64 * 64];       // 16 KB
  __shared__ u16 Vs[2][64 * 64];       // 16 KB
  __shared__ u16 Ps[2][2][16 * 64];    //  8 KB (per-wave, per-group P tile)
  const int tid = threadIdx.x, wid = tid >> 6, lane = tid & 63;
  const int fq = lane >> 4, fr = lane & 15;
  const int bh = blockIdx.x;
  const int bq = (NQT - 1) - blockIdx.y;   // LPT: heaviest tiles dispatch first
  const int b = bh / Hz, h = bh % Hz;
  const int qbase = bq * 64 + wid * 32;    // wave's first q-row
  const int nkt = bq + 1;

  const u16* Kg = Kh + (size_t)bh * Sz * DHz;
  const u16* Vg = Vt + (size_t)bh * DHz * Sz;
  const u16* Qg = Qh + (size_t)bh * Sz * DHz;

  bf16x8 aq[2][2];
#pragma unroll
  for (int g = 0; g < 2; ++g)
#pragma unroll
    for (int kk = 0; kk < 2; ++kk)
      aq[g][kk] = *(const bf16x8*)(Qg + (qbase + g * 16 + fr) * DHz + kk * 32 + fq * 8);

  const f32x4 zero = {0.f, 0.f, 0.f, 0.f};
  f32x4 o[2][4];
#pragma unroll
  for (int g = 0; g < 2; ++g)
#pragma unroll
    for (int i = 0; i < 4; ++i) o[g][i] = zero;
  float m_r[2][4], l_r[2][4];
#pragma unroll
  for (int g = 0; g < 2; ++g)
#pragma unroll
    for (int r = 0; r < 4; ++r) { m_r[g][r] = -1e30f; l_r[g][r] = 0.f; }

  char* Pw[2] = { (char*)Ps[wid][0], (char*)Ps[wid][1] };

  stage_kv(Kg, Vg, 0, Ks[0], Vs[0], wid, lane);
  int cur = 0;

  for (int kt = 0; kt < nkt; ++kt) {
    __syncthreads();   // stage(kt) drained (vmcnt in syncthreads); prev reads done
    if (kt + 1 < nkt)
      stage_kv(Kg, Vg, kt + 1, Ks[cur ^ 1], Vs[cur ^ 1], wid, lane);

    const char* Kb = (const char*)Ks[cur];
    const char* Vb = (const char*)Vs[cur];

    // shared K fragments
    bf16x8 kfr[4][2];
#pragma unroll
    for (int j = 0; j < 4; ++j) {
      int rowK = j * 16 + fr;
#pragma unroll
      for (int kk = 0; kk < 2; ++kk)
        kfr[j][kk] = *(const bf16x8*)(Kb + rowK * 128 + ((kk * 64 + fq * 16) ^ ((rowK & 7) << 4)));
    }
    // shared V fragments (issued early; consumed after softmax)
    bf16x8 vfr[4][2];
#pragma unroll
    for (int fo = 0; fo < 4; ++fo) {
      int rowV = fo * 16 + fr;
#pragma unroll
      for (int kk = 0; kk < 2; ++kk)
        vfr[fo][kk] = *(const bf16x8*)(Vb + rowV * 128 + ((kk * 64 + fq * 16) ^ ((rowV & 7) << 4)));
    }

    // QK for BOTH groups, one MFMA cluster
    f32x4 s[2][4];
#pragma unroll
    for (int g = 0; g < 2; ++g)
#pragma unroll
      for (int j = 0; j < 4; ++j) s[g][j] = zero;
    __builtin_amdgcn_s_setprio(1);
#pragma unroll
    for (int j = 0; j < 4; ++j)
#pragma unroll
      for (int g = 0; g < 2; ++g)
#pragma unroll
        for (int kk = 0; kk < 2; ++kk)
          s[g][j] = mfma16(aq[g][kk], kfr[j][kk], s[g][j]);
    __builtin_amdgcn_s_setprio(0);

    // causal mask only on the diagonal tile (block-uniform branch)
    if (kt == bq) {
#pragma unroll
      for (int g = 0; g < 2; ++g)
#pragma unroll
        for (int j = 0; j < 4; ++j) {
          int keyg = kt * 64 + j * 16 + fr;
#pragma unroll
          for (int r = 0; r < 4; ++r)
            if (keyg > qbase + g * 16 + fq * 4 + r) s[g][j][r] = -1e30f;
        }
    }

    // per-lane partial max, both groups (independent chains)
    float mt[2][4];
#pragma unroll
    for (int g = 0; g < 2; ++g) {
#pragma unroll
      for (int r = 0; r < 4; ++r) mt[g][r] = s[g][0][r];
#pragma unroll
      for (int j = 1; j < 4; ++j)
#pragma unroll
        for (int r = 0; r < 4; ++r) mt[g][r] = fmaxf(mt[g][r], s[g][j][r]);
    }
    int nd = 0;
#pragma unroll
    for (int g = 0; g < 2; ++g)
#pragma unroll
      for (int r = 0; r < 4; ++r) nd |= (mt[g][r] > m_r[g][r] + 8.f) ? 1 : 0;
    if (__any(nd)) {
#pragma unroll
      for (int msk = 1; msk < 16; msk <<= 1)
#pragma unroll
        for (int g = 0; g < 2; ++g)
#pragma unroll
          for (int r = 0; r < 4; ++r) mt[g][r] = fmaxf(mt[g][r], __shfl_xor(mt[g][r], msk));
#pragma unroll
      for (int g = 0; g < 2; ++g)
#pragma unroll
        for (int r = 0; r < 4; ++r) {
          float mn = fmaxf(m_r[g][r], mt[g][r]);
          float alpha = __builtin_amdgcn_exp2f(m_r[g][r] - mn);
          m_r[g][r] = mn;
          l_r[g][r] *= alpha;
#pragma unroll
          for (int i = 0; i < 4; ++i) o[g][i][r] *= alpha;
        }
    }

    // P = exp2(S - m) for both groups, interleaved (independent streams)
#pragma unroll
    for (int j = 0; j < 4; ++j)
#pragma unroll
      for (int g = 0; g < 2; ++g)
#pragma unroll
        for (int r = 0; r < 4; ++r) {
          float e = __builtin_amdgcn_exp2f(s[g][j][r] - m_r[g][r]);
          l_r[g][r] += e;
          int qr = fq * 4 + r;
          int key2 = (j * 16 + fr) * 2;
          *(u16*)(Pw[g] + qr * 128 + (key2 ^ ((qr & 7) << 4))) = f2bf(e);
        }

    // PV for BOTH groups, one MFMA cluster
    __builtin_amdgcn_s_setprio(1);
#pragma unroll
    for (int kk = 0; kk < 2; ++kk) {
#pragma unroll
      for (int g = 0; g < 2; ++g) {
        int cbP = (kk * 64 + fq * 16) ^ ((fr & 7) << 4);
        bf16x8 pa = *(const bf16x8*)(Pw[g] + fr * 128 + cbP);
#pragma unroll
        for (int fo = 0; fo < 4; ++fo)
          o[g][fo] = mfma16(pa, vfr[fo][kk], o[g][fo]);
      }
    }
    __builtin_amdgcn_s_setprio(0);
    cur ^= 1;
  }

  // final l reduce (once) + normalize + write ctx [B,S,D] bf16
#pragma unroll
  for (int msk = 1; msk < 16; msk <<= 1)
#pragma unroll
    for (int g = 0; g < 2; ++g)
#pragma unroll
      for (int r = 0; r < 4; ++r) l_r[g][r] += __shfl_xor(l_r[g][r], msk);

#pragma unroll
  for (int g = 0; g < 2; ++g) {
#pragma unroll
    for (int fo = 0; fo < 4; ++fo) {
      int dh = fo * 16 + fr;
#pragma unroll
      for (int r = 0; r < 4; ++r) {
        int qg = qbase + g * 16 + fq * 4 + r;
        ctx[((size_t)b * Sz + qg) * Dz + h * DHz + dh] = f2bf(o[g][fo][r] / l_r[g][r]);
      }
    }
  }
}

// ---------------- launch ----------------
extern "C" void kernel_launch(void* const* d_in, const int* in_sizes, int n_in,
                              void* d_out, int out_size, void* d_ws, size_t ws_size,
                              hipStream_t stream) {
  const float* q  = (const float*)d_in[0];
  const float* k  = (const float*)d_in[1];
  const float* v  = (const float*)d_in[2];
  const float* Wq = (const float*)d_in[3];
  const float* bq = (const float*)d_in[4];
  const float* Wk = (const float*)d_in[5];
  const float* bk = (const float*)d_in[6];
  const float* Wv = (const float*)d_in[7];
  const float* bv = (const float*)d_in[8];
  const float* Wo = (const float*)d_in[9];
  const float* bo = (const float*)d_in[10];
  float* out = (float*)d_out;

  char* ws = (char*)d_ws;
  size_t off = 0;
  auto alloc = [&](size_t bytes) {
    void* p = ws + off;
    off += (bytes + 255) & ~(size_t)255;
    return p;
  };
  u16* qb  = (u16*)alloc((size_t)Mz * Dz * 2);
  u16* kb  = (u16*)alloc((size_t)Mz * Dz * 2);
  u16* vb  = (u16*)alloc((size_t)Mz * Dz * 2);
  u16* Wqt = (u16*)alloc((size_t)Dz * Dz * 2);
  u16* Wkt = (u16*)alloc((size_t)Dz * Dz * 2);
  u16* Wvt = (u16*)alloc((size_t)Dz * Dz * 2);
  u16* Wot = (u16*)alloc((size_t)Dz * Dz * 2);
  u16* Qh  = (u16*)alloc((size_t)Bz * Hz * Sz * DHz * 2);
  u16* Kh  = (u16*)alloc((size_t)Bz * Hz * Sz * DHz * 2);
  u16* Vtr = (u16*)alloc((size_t)Bz * Hz * DHz * Sz * 2);
  u16* ctx = (u16*)alloc((size_t)Mz * Dz * 2);

  int n8 = Mz * Dz / 8;
  int cblk = (n8 + 255) / 256;
  cvt3_kernel<<<dim3(cblk, 3), 256, 0, stream>>>(q, k, v, qb, kb, vb, n8);

  wtrans4_kernel<<<dim3(Dz / 32, Dz / 32, 4), 256, 0, stream>>>(
      Wq, Wk, Wv, Wo, Wqt, Wkt, Wvt, Wot);

  gemm_qkv<<<dim3(Mz / 128, Dz / 128, 3), 256, 0, stream>>>(
      qb, kb, vb, Wqt, Wkt, Wvt, bq, bk, bv, Qh, Kh, Vtr);

  attn_kernel<<<dim3(Bz * Hz, NQT), 128, 0, stream>>>(Qh, Kh, Vtr, ctx);

  gemm_out_k<<<dim3(Mz / 128, Dz / 128), 256, 0, stream>>>(ctx, Wot, bo, out);
}

// Round 12
// 112.815 us; speedup vs baseline: 1.0352x; 1.0352x over previous
//
#include <hip/hip_runtime.h>
#include <hip/hip_bf16.h>
#include <stdint.h>

#define Bz 2
#define Sz 2048
#define Dz 768
#define Hz 12
#define DHz 64
#define Mz (Bz*Sz)    // 4096
#define NQT2 64       // 32-row q-tiles per (b,h)

typedef __attribute__((ext_vector_type(4))) float f32x4;
typedef __attribute__((ext_vector_type(8))) short bf16x8;
typedef unsigned short u16;
typedef __attribute__((ext_vector_type(8))) unsigned short u16x8;

__device__ __forceinline__ u16 f2bf(float f) {
  union { float f; uint32_t u; } c; c.f = f;
  uint32_t u = c.u;
  return (u16)((u + 0x7fffu + ((u >> 16) & 1u)) >> 16);
}

#define GLL16(gsrc, ldst) \
  __builtin_amdgcn_global_load_lds((const __attribute__((address_space(1))) void*)(gsrc), \
                                   (__attribute__((address_space(3))) void*)(ldst), 16, 0, 0)

__device__ __forceinline__ f32x4 mfma16(bf16x8 a, bf16x8 b, f32x4 c) {
  return __builtin_amdgcn_mfma_f32_16x16x32_bf16(a, b, c, 0, 0, 0);
}

// ---------------- pre-pass: fp32 -> bf16 (q,k,v fused in one launch) ----------------
__global__ void cvt3_kernel(const float* __restrict__ qa, const float* __restrict__ ka,
                            const float* __restrict__ va,
                            u16* __restrict__ qo, u16* __restrict__ ko, u16* __restrict__ vo,
                            int n8) {
  int i = blockIdx.x * blockDim.x + threadIdx.x;
  if (i >= n8) return;
  int z = blockIdx.y;
  const float* src = (z == 0) ? qa : (z == 1) ? ka : va;
  u16* dst = (z == 0) ? qo : (z == 1) ? ko : vo;
  const float4* s4 = (const float4*)src;
  float4 a = s4[(size_t)i * 2];
  float4 b = s4[(size_t)i * 2 + 1];
  u16x8 o;
  o[0] = f2bf(a.x); o[1] = f2bf(a.y); o[2] = f2bf(a.z); o[3] = f2bf(a.w);
  o[4] = f2bf(b.x); o[5] = f2bf(b.y); o[6] = f2bf(b.z); o[7] = f2bf(b.w);
  *(u16x8*)(dst + (size_t)i * 8) = o;
}

// ---------------- pre-pass: W [K][N] fp32 -> Wt [N][K] bf16 (4 weights fused) ----------------
__global__ void wtrans4_kernel(const float* __restrict__ W0, const float* __restrict__ W1,
                               const float* __restrict__ W2, const float* __restrict__ W3,
                               u16* __restrict__ T0, u16* __restrict__ T1,
                               u16* __restrict__ T2, u16* __restrict__ T3) {
  __shared__ float tile[32][33];
  int z = blockIdx.z;
  const float* W = (z == 0) ? W0 : (z == 1) ? W1 : (z == 2) ? W2 : W3;
  u16* Wt = (z == 0) ? T0 : (z == 1) ? T1 : (z == 2) ? T2 : T3;
  int bx = blockIdx.x * 32, by = blockIdx.y * 32;
  int tx = threadIdx.x & 31, ty = threadIdx.x >> 5;   // 256 threads: ty 0..7
#pragma unroll
  for (int i = 0; i < 32; i += 8)
    tile[ty + i][tx] = W[(size_t)(by + ty + i) * Dz + bx + tx];
  __syncthreads();
#pragma unroll
  for (int i = 0; i < 32; i += 8)
    Wt[(size_t)(bx + ty + i) * Dz + by + tx] = f2bf(tile[tx][ty + i]);
}

// ---------------- GEMM core, 64x128 tile: C[M][N] = A[M][K] * Wt[N][K]^T + bias ----------------
// Triple-buffered, ONE raw barrier per K-step, counted vmcnt(3) (3 loads/thread/step).
// 4 waves: wave (wm,wn) owns a 32x64 sub-tile -> acc[2][4]. LDS 36 KB -> 4 blocks/CU.
// mode 0: bf16 out [B,H,S,DH] (Q,K proj; out=(acc+bias)*oscale)
// mode 1: bf16 out [B,H,DH,S] (V proj, transposed)
// mode 2: fp32 out [M][N]     (output projection)
__device__ __forceinline__ void gemm_core64(
    const u16* __restrict__ A, const u16* __restrict__ Wt,
    const float* __restrict__ bias, void* __restrict__ out, int mode, float oscale,
    u16 (*As)[64 * 32], u16 (*Bs)[128 * 32])
{
  const int tid = threadIdx.x;
  const int wid = tid >> 6, lane = tid & 63;
  const int wm = wid >> 1, wn = wid & 1;
  const int m0 = blockIdx.x * 64, n0 = blockIdx.y * 128;
  const int fq = lane >> 4, fr = lane & 15;

  // A staging: one 16B load/thread covers the 4KB tile
  int aoff;
  {
    int off  = tid * 16;
    int row  = off >> 6;
    int colb = (off & 63) ^ (((row >> 1) & 3) << 4);
    aoff = row * Dz + (colb >> 1);
  }
  // B staging: two 16B loads/thread cover the 8KB tile
  int boff[2];
#pragma unroll
  for (int c = 0; c < 2; ++c) {
    int off  = tid * 16 + c * 4096;
    int row  = off >> 6;
    int colb = (off & 63) ^ (((row >> 1) & 3) << 4);
    boff[c] = row * Dz + (colb >> 1);
  }

  int raddr[2], rbaddr[4];
#pragma unroll
  for (int f = 0; f < 2; ++f) {
    int rowA = wm * 32 + f * 16 + fr;
    raddr[f] = rowA * 64 + ((fq * 16) ^ (((rowA >> 1) & 3) << 4));
  }
#pragma unroll
  for (int f = 0; f < 4; ++f) {
    int rowB = wn * 64 + f * 16 + fr;
    rbaddr[f] = rowB * 64 + ((fq * 16) ^ (((rowB >> 1) & 3) << 4));
  }

  f32x4 acc[2][4];
  const f32x4 zero = {0.f, 0.f, 0.f, 0.f};
#pragma unroll
  for (int i = 0; i < 2; ++i)
#pragma unroll
    for (int j = 0; j < 4; ++j) acc[i][j] = zero;

  const u16* Abase = A + (size_t)m0 * Dz;
  const u16* Bbase = Wt + (size_t)n0 * Dz;

  const int NKT = Dz / 32;   // 24
  // prologue: stage tile 0 into buf 0 (3 loads/thread)
  GLL16(Abase + aoff, (char*)As[0] + tid * 16);
#pragma unroll
  for (int c = 0; c < 2; ++c)
    GLL16(Bbase + boff[c], (char*)Bs[0] + tid * 16 + c * 4096);
  int cur = 0;

  for (int kt = 0; kt < NKT; ++kt) {
    int nx = cur + 1; if (nx == 3) nx = 0;
    if (kt + 1 < NKT) {
      int ke = (kt + 1) * 32;
      GLL16(Abase + ke + aoff, (char*)As[nx] + tid * 16);
#pragma unroll
      for (int c = 0; c < 2; ++c)
        GLL16(Bbase + ke + boff[c], (char*)Bs[nx] + tid * 16 + c * 4096);
      asm volatile("s_waitcnt vmcnt(3)" ::: "memory");  // tile kt landed; kt+1 in flight
    } else {
      asm volatile("s_waitcnt vmcnt(0)" ::: "memory");
    }
    __builtin_amdgcn_s_barrier();
    __builtin_amdgcn_sched_barrier(0);

    bf16x8 af[2], bf[4];
#pragma unroll
    for (int f = 0; f < 2; ++f)
      af[f] = *(const bf16x8*)((const char*)As[cur] + raddr[f]);
#pragma unroll
    for (int f = 0; f < 4; ++f)
      bf[f] = *(const bf16x8*)((const char*)Bs[cur] + rbaddr[f]);
    __builtin_amdgcn_s_setprio(1);
#pragma unroll
    for (int i = 0; i < 2; ++i)
#pragma unroll
      for (int j = 0; j < 4; ++j)
        acc[i][j] = mfma16(af[i], bf[j], acc[i][j]);
    __builtin_amdgcn_s_setprio(0);
    cur = nx;
  }

  if (mode == 2) {
    float* O = (float*)out;
#pragma unroll
    for (int i = 0; i < 2; ++i) {
      int grow = m0 + wm * 32 + i * 16 + fq * 4;
#pragma unroll
      for (int j = 0; j < 4; ++j) {
        int gcol = n0 + wn * 64 + j * 16 + fr;
        float bv = bias[gcol];
#pragma unroll
        for (int r = 0; r < 4; ++r)
          O[(size_t)(grow + r) * Dz + gcol] = acc[i][j][r] + bv;
      }
    }
  } else {
    u16* O = (u16*)out;
#pragma unroll
    for (int i = 0; i < 2; ++i) {
      int grow = m0 + wm * 32 + i * 16 + fq * 4;
#pragma unroll
      for (int j = 0; j < 4; ++j) {
        int gcol = n0 + wn * 64 + j * 16 + fr;
        float bv = bias[gcol];
        int h = gcol >> 6, dh = gcol & 63;
#pragma unroll
        for (int r = 0; r < 4; ++r) {
          int t = grow + r;
          int b = t >> 11, s = t & 2047;
          float v = (acc[i][j][r] + bv) * oscale;
          if (mode == 0)
            O[((size_t)(b * Hz + h) * Sz + s) * DHz + dh] = f2bf(v);
          else
            O[((size_t)(b * Hz + h) * DHz + dh) * Sz + s] = f2bf(v);
        }
      }
    }
  }
}

// Q is pre-scaled by 1/sqrt(DH) * log2(e) so attention can use raw v_exp_f32 (exp2)
#define QSCALE 0.1803368801111404f   // 0.125 * 1.4426950408889634

__global__ __launch_bounds__(256, 4) void gemm_qkv(
    const u16* __restrict__ qb, const u16* __restrict__ kb, const u16* __restrict__ vb,
    const u16* __restrict__ Wqt, const u16* __restrict__ Wkt, const u16* __restrict__ Wvt,
    const float* __restrict__ bq, const float* __restrict__ bk, const float* __restrict__ bv,
    u16* __restrict__ Qh, u16* __restrict__ Kh, u16* __restrict__ Vt)
{
  __shared__ u16 As[3][64 * 32];
  __shared__ u16 Bs[3][128 * 32];
  const u16* A; const u16* W; const float* bias; u16* out; int mode; float osc;
  if (blockIdx.z == 0)      { A = qb; W = Wqt; bias = bq; out = Qh; mode = 0; osc = QSCALE; }
  else if (blockIdx.z == 1) { A = kb; W = Wkt; bias = bk; out = Kh; mode = 0; osc = 1.f; }
  else                      { A = vb; W = Wvt; bias = bv; out = Vt; mode = 1; osc = 1.f; }
  gemm_core64(A, W, bias, out, mode, osc, As, Bs);
}

__global__ __launch_bounds__(256, 4) void gemm_out_k(
    const u16* __restrict__ ctx, const u16* __restrict__ Wot,
    const float* __restrict__ bo, float* __restrict__ out)
{
  __shared__ u16 As[3][64 * 32];
  __shared__ u16 Bs[3][128 * 32];
  gemm_core64(ctx, Wot, bo, (void*)out, 2, 1.f, As, Bs);
}

// ---------------- flash attention (R10, proven): paired 32-row q-tiles ----------------
// grid (B*H, NQT2/2) = (24, 32) = 768 blocks of 128 threads (2 waves).
// Block p handles q-tiles {p, 63-p}; triple-buffered K/V, one raw barrier per
// k-tile, counted vmcnt(8) so next tile's loads stay in flight across it.
__device__ __forceinline__ void stage_kv(const u16* __restrict__ Kg, const u16* __restrict__ Vg,
                                         int kt, u16* Ks, u16* Vs, int wid, int lane) {
#pragma unroll
  for (int c = 0; c < 4; ++c) {
    int off  = (wid * 4 + c) * 1024 + lane * 16;
    int row  = off >> 7;                       // 128B rows (64 bf16)
    int colb = (off & 127) ^ ((row & 7) << 4); // XOR swizzle bits 4-6
    GLL16(Kg + ((size_t)(kt * 64 + row)) * DHz + (colb >> 1), (char*)Ks + (wid * 4 + c) * 1024);
    GLL16(Vg + (size_t)row * Sz + kt * 64 + (colb >> 1),      (char*)Vs + (wid * 4 + c) * 1024);
  }
}

// one 16-row group's work for one staged k-tile
__device__ __forceinline__ void attn_group(
    const bf16x8* aq, const bf16x8 kfr[4][2], const bf16x8 vfr[4][2],
    f32x4* o, float* m_r, float* l_r, char* Pw,
    int qbase, int kt, bool diag, int fq, int fr)
{
  const f32x4 zero = {0.f, 0.f, 0.f, 0.f};
  f32x4 s[4];
#pragma unroll
  for (int j = 0; j < 4; ++j) s[j] = zero;
  __builtin_amdgcn_s_setprio(1);
#pragma unroll
  for (int j = 0; j < 4; ++j)
#pragma unroll
    for (int kk = 0; kk < 2; ++kk)
      s[j] = mfma16(aq[kk], kfr[j][kk], s[j]);
  __builtin_amdgcn_s_setprio(0);

  if (diag) {
#pragma unroll
    for (int j = 0; j < 4; ++j) {
      int keyg = kt * 64 + j * 16 + fr;
#pragma unroll
      for (int r = 0; r < 4; ++r)
        if (keyg > qbase + fq * 4 + r) s[j][r] = -1e30f;
    }
  }

  float mt[4];
#pragma unroll
  for (int r = 0; r < 4; ++r) mt[r] = s[0][r];
#pragma unroll
  for (int j = 1; j < 4; ++j)
#pragma unroll
    for (int r = 0; r < 4; ++r) mt[r] = fmaxf(mt[r], s[j][r]);

  int nd = 0;
#pragma unroll
  for (int r = 0; r < 4; ++r) nd |= (mt[r] > m_r[r] + 8.f) ? 1 : 0;
  if (__any(nd)) {
#pragma unroll
    for (int msk = 1; msk < 16; msk <<= 1)
#pragma unroll
      for (int r = 0; r < 4; ++r) mt[r] = fmaxf(mt[r], __shfl_xor(mt[r], msk));
#pragma unroll
    for (int r = 0; r < 4; ++r) {
      float mn = fmaxf(m_r[r], mt[r]);
      float alpha = __builtin_amdgcn_exp2f(m_r[r] - mn);
      m_r[r] = mn;
      l_r[r] *= alpha;
#pragma unroll
      for (int i = 0; i < 4; ++i) o[i][r] *= alpha;
    }
  }

#pragma unroll
  for (int j = 0; j < 4; ++j) {
#pragma unroll
    for (int r = 0; r < 4; ++r) {
      float e = __builtin_amdgcn_exp2f(s[j][r] - m_r[r]);
      l_r[r] += e;
      int qr = fq * 4 + r;
      int key2 = (j * 16 + fr) * 2;
      *(u16*)(Pw + qr * 128 + (key2 ^ ((qr & 7) << 4))) = f2bf(e);
    }
  }

  __builtin_amdgcn_s_setprio(1);
#pragma unroll
  for (int kk = 0; kk < 2; ++kk) {
    int cbP = (kk * 64 + fq * 16) ^ ((fr & 7) << 4);
    bf16x8 pa = *(const bf16x8*)(Pw + fr * 128 + cbP);
#pragma unroll
    for (int fo = 0; fo < 4; ++fo)
      o[fo] = mfma16(pa, vfr[fo][kk], o[fo]);
  }
  __builtin_amdgcn_s_setprio(0);
}

__global__ __launch_bounds__(128, 2) void attn_kernel(
    const u16* __restrict__ Qh, const u16* __restrict__ Kh,
    const u16* __restrict__ Vt, u16* __restrict__ ctx)
{
  __shared__ u16 Ks[3][64 * 64];     // 24 KB
  __shared__ u16 Vs[3][64 * 64];     // 24 KB
  __shared__ u16 Ps[2 * 16 * 64];    //  4 KB (per-wave P, reused by both groups)
  const int tid = threadIdx.x, wid = tid >> 6, lane = tid & 63;
  const int fq = lane >> 4, fr = lane & 15;
  const int bh = blockIdx.x;
  const int p = blockIdx.y;            // pair index 0..31
  const int b = bh / Hz, h = bh % Hz;
  const int qb0 = p * 32 + wid * 16;                 // low q-tile rows (this wave)
  const int qb1 = (NQT2 - 1 - p) * 32 + wid * 16;    // high q-tile rows
  const int nkt = ((NQT2 - p) * 32 + 63) / 64;       // staged k-tiles (covers high)
  const int nlo = ((p + 1) * 32 + 63) / 64;          // low group active iterations

  const u16* Kg = Kh + (size_t)bh * Sz * DHz;
  const u16* Vg = Vt + (size_t)bh * DHz * Sz;
  const u16* Qg = Qh + (size_t)bh * Sz * DHz;

  bf16x8 aq[2][2];
#pragma unroll
  for (int kk = 0; kk < 2; ++kk) {
    aq[0][kk] = *(const bf16x8*)(Qg + (qb0 + fr) * DHz + kk * 32 + fq * 8);
    aq[1][kk] = *(const bf16x8*)(Qg + (qb1 + fr) * DHz + kk * 32 + fq * 8);
  }

  const f32x4 zero = {0.f, 0.f, 0.f, 0.f};
  f32x4 o[2][4];
#pragma unroll
  for (int g = 0; g < 2; ++g)
#pragma unroll
    for (int i = 0; i < 4; ++i) o[g][i] = zero;
  float m_r[2][4], l_r[2][4];
#pragma unroll
  for (int g = 0; g < 2; ++g)
#pragma unroll
    for (int r = 0; r < 4; ++r) { m_r[g][r] = -1e30f; l_r[g][r] = 0.f; }

  char* Pw = (char*)(Ps + wid * 16 * 64);

  stage_kv(Kg, Vg, 0, Ks[0], Vs[0], wid, lane);
  int cur = 0;

  for (int kt = 0; kt < nkt; ++kt) {
    int nx = cur + 1; if (nx == 3) nx = 0;
    if (kt + 1 < nkt) {
      stage_kv(Kg, Vg, kt + 1, Ks[nx], Vs[nx], wid, lane);
      asm volatile("s_waitcnt vmcnt(8)" ::: "memory");
    } else {
      asm volatile("s_waitcnt vmcnt(0)" ::: "memory");
    }
    __builtin_amdgcn_s_barrier();
    __builtin_amdgcn_sched_barrier(0);

    const char* Kb = (const char*)Ks[cur];
    const char* Vb = (const char*)Vs[cur];

    bf16x8 kfr[4][2];
#pragma unroll
    for (int j = 0; j < 4; ++j) {
      int rowK = j * 16 + fr;
#pragma unroll
      for (int kk = 0; kk < 2; ++kk)
        kfr[j][kk] = *(const bf16x8*)(Kb + rowK * 128 + ((kk * 64 + fq * 16) ^ ((rowK & 7) << 4)));
    }
    bf16x8 vfr[4][2];
#pragma unroll
    for (int fo = 0; fo < 4; ++fo) {
      int rowV = fo * 16 + fr;
#pragma unroll
      for (int kk = 0; kk < 2; ++kk)
        vfr[fo][kk] = *(const bf16x8*)(Vb + rowV * 128 + ((kk * 64 + fq * 16) ^ ((rowV & 7) << 4)));
    }

    if (kt < nlo)
      attn_group(aq[0], kfr, vfr, o[0], m_r[0], l_r[0], Pw, qb0, kt, kt == nlo - 1, fq, fr);
    attn_group(aq[1], kfr, vfr, o[1], m_r[1], l_r[1], Pw, qb1, kt, kt == nkt - 1, fq, fr);

    cur = nx;
  }

#pragma unroll
  for (int msk = 1; msk < 16; msk <<= 1)
#pragma unroll
    for (int g = 0; g < 2; ++g)
#pragma unroll
      for (int r = 0; r < 4; ++r) l_r[g][r] += __shfl_xor(l_r[g][r], msk);

#pragma unroll
  for (int g = 0; g < 2; ++g) {
    int qb = (g == 0) ? qb0 : qb1;
#pragma unroll
    for (int fo = 0; fo < 4; ++fo) {
      int dh = fo * 16 + fr;
#pragma unroll
      for (int r = 0; r < 4; ++r) {
        int qg = qb + fq * 4 + r;
        ctx[((size_t)b * Sz + qg) * Dz + h * DHz + dh] = f2bf(o[g][fo][r] / l_r[g][r]);
      }
    }
  }
}

// ---------------- launch ----------------
extern "C" void kernel_launch(void* const* d_in, const int* in_sizes, int n_in,
                              void* d_out, int out_size, void* d_ws, size_t ws_size,
                              hipStream_t stream) {
  const float* q  = (const float*)d_in[0];
  const float* k  = (const float*)d_in[1];
  const float* v  = (const float*)d_in[2];
  const float* Wq = (const float*)d_in[3];
  const float* bq = (const float*)d_in[4];
  const float* Wk = (const float*)d_in[5];
  const float* bk = (const float*)d_in[6];
  const float* Wv = (const float*)d_in[7];
  const float* bv = (const float*)d_in[8];
  const float* Wo = (const float*)d_in[9];
  const float* bo = (const float*)d_in[10];
  float* out = (float*)d_out;

  char* ws = (char*)d_ws;
  size_t off = 0;
  auto alloc = [&](size_t bytes) {
    void* p = ws + off;
    off += (bytes + 255) & ~(size_t)255;
    return p;
  };
  u16* qb  = (u16*)alloc((size_t)Mz * Dz * 2);
  u16* kb  = (u16*)alloc((size_t)Mz * Dz * 2);
  u16* vb  = (u16*)alloc((size_t)Mz * Dz * 2);
  u16* Wqt = (u16*)alloc((size_t)Dz * Dz * 2);
  u16* Wkt = (u16*)alloc((size_t)Dz * Dz * 2);
  u16* Wvt = (u16*)alloc((size_t)Dz * Dz * 2);
  u16* Wot = (u16*)alloc((size_t)Dz * Dz * 2);
  u16* Qh  = (u16*)alloc((size_t)Bz * Hz * Sz * DHz * 2);
  u16* Kh  = (u16*)alloc((size_t)Bz * Hz * Sz * DHz * 2);
  u16* Vtr = (u16*)alloc((size_t)Bz * Hz * DHz * Sz * 2);
  u16* ctx = (u16*)alloc((size_t)Mz * Dz * 2);

  int n8 = Mz * Dz / 8;
  int cblk = (n8 + 255) / 256;
  cvt3_kernel<<<dim3(cblk, 3), 256, 0, stream>>>(q, k, v, qb, kb, vb, n8);

  wtrans4_kernel<<<dim3(Dz / 32, Dz / 32, 4), 256, 0, stream>>>(
      Wq, Wk, Wv, Wo, Wqt, Wkt, Wvt, Wot);

  gemm_qkv<<<dim3(Mz / 64, Dz / 128, 3), 256, 0, stream>>>(
      qb, kb, vb, Wqt, Wkt, Wvt, bq, bk, bv, Qh, Kh, Vtr);

  attn_kernel<<<dim3(Bz * Hz, NQT2 / 2), 128, 0, stream>>>(Qh, Kh, Vtr, ctx);

  gemm_out_k<<<dim3(Mz / 64, Dz / 128), 256, 0, stream>>>(ctx, Wot, bo, out);
}

// Round 13
// 98.106 us; speedup vs baseline: 1.1904x; 1.1499x over previous
//
#include <hip/hip_runtime.h>
#include <hip/hip_bf16.h>
#include <stdint.h>

#define Bz 2
#define Sz 2048
#define Dz 768
#define Hz 12
#define DHz 64
#define Mz (Bz*Sz)    // 4096
#define NQT2 64       // 32-row q-tiles per (b,h)

typedef __attribute__((ext_vector_type(4))) float f32x4;
typedef __attribute__((ext_vector_type(8))) short bf16x8;
typedef unsigned short u16;
typedef __attribute__((ext_vector_type(8))) unsigned short u16x8;

__device__ __forceinline__ u16 f2bf(float f) {
  union { float f; uint32_t u; } c; c.f = f;
  uint32_t u = c.u;
  return (u16)((u + 0x7fffu + ((u >> 16) & 1u)) >> 16);
}

#define GLL16(gsrc, ldst) \
  __builtin_amdgcn_global_load_lds((const __attribute__((address_space(1))) void*)(gsrc), \
                                   (__attribute__((address_space(3))) void*)(ldst), 16, 0, 0)

__device__ __forceinline__ f32x4 mfma16(bf16x8 a, bf16x8 b, f32x4 c) {
  return __builtin_amdgcn_mfma_f32_16x16x32_bf16(a, b, c, 0, 0, 0);
}

// ---------------- pre-pass: fp32 -> bf16 (q,k,v fused in one launch) ----------------
__global__ void cvt3_kernel(const float* __restrict__ qa, const float* __restrict__ ka,
                            const float* __restrict__ va,
                            u16* __restrict__ qo, u16* __restrict__ ko, u16* __restrict__ vo,
                            int n8) {
  int i = blockIdx.x * blockDim.x + threadIdx.x;
  if (i >= n8) return;
  int z = blockIdx.y;
  const float* src = (z == 0) ? qa : (z == 1) ? ka : va;
  u16* dst = (z == 0) ? qo : (z == 1) ? ko : vo;
  const float4* s4 = (const float4*)src;
  float4 a = s4[(size_t)i * 2];
  float4 b = s4[(size_t)i * 2 + 1];
  u16x8 o;
  o[0] = f2bf(a.x); o[1] = f2bf(a.y); o[2] = f2bf(a.z); o[3] = f2bf(a.w);
  o[4] = f2bf(b.x); o[5] = f2bf(b.y); o[6] = f2bf(b.z); o[7] = f2bf(b.w);
  *(u16x8*)(dst + (size_t)i * 8) = o;
}

// ---------------- pre-pass: W [K][N] fp32 -> Wt [N][K] bf16 (4 weights fused) ----------------
__global__ void wtrans4_kernel(const float* __restrict__ W0, const float* __restrict__ W1,
                               const float* __restrict__ W2, const float* __restrict__ W3,
                               u16* __restrict__ T0, u16* __restrict__ T1,
                               u16* __restrict__ T2, u16* __restrict__ T3) {
  __shared__ float tile[32][33];
  int z = blockIdx.z;
  const float* W = (z == 0) ? W0 : (z == 1) ? W1 : (z == 2) ? W2 : W3;
  u16* Wt = (z == 0) ? T0 : (z == 1) ? T1 : (z == 2) ? T2 : T3;
  int bx = blockIdx.x * 32, by = blockIdx.y * 32;
  int tx = threadIdx.x & 31, ty = threadIdx.x >> 5;   // 256 threads: ty 0..7
#pragma unroll
  for (int i = 0; i < 32; i += 8)
    tile[ty + i][tx] = W[(size_t)(by + ty + i) * Dz + bx + tx];
  __syncthreads();
#pragma unroll
  for (int i = 0; i < 32; i += 8)
    Wt[(size_t)(bx + ty + i) * Dz + by + tx] = f2bf(tile[tx][ty + i]);
}

// ---------------- GEMM core (R10, proven): 128x128, triple-buffer, 1 barrier, counted vmcnt ----
// mode 0: Q -> fragment layout Qf[bh][qt=s>>4][kk=dh>>5][lane][e]         (scaled by oscale)
// mode 3: K -> fragment layout Kf[bh][kt=s>>6][j=(s>>4)&3][kk=dh>>5][lane][e]
// mode 1: V -> fragment layout Vf[bh][kt=s>>6][fo=dh>>4][kk=(s>>5)&1][lane][e]
// mode 2: fp32 out [M][N] (output projection)
__device__ __forceinline__ void gemm_core(
    const u16* __restrict__ A, const u16* __restrict__ Wt,
    const float* __restrict__ bias, void* __restrict__ out, int mode, float oscale,
    u16 (*As)[128 * 32], u16 (*Bs)[128 * 32])
{
  const int tid = threadIdx.x;
  const int wid = tid >> 6, lane = tid & 63;
  const int wm = wid >> 1, wn = wid & 1;
  const int m0 = blockIdx.x * 128, n0 = blockIdx.y * 128;
  const int fq = lane >> 4, fr = lane & 15;

  int aoff[2];
#pragma unroll
  for (int c = 0; c < 2; ++c) {
    int off  = (wid * 2 + c) * 1024 + lane * 16;
    int row  = off >> 6;
    int colb = (off & 63) ^ (((row >> 1) & 3) << 4);
    aoff[c]  = row * Dz + (colb >> 1);
  }

  int raddr[4], rbaddr[4];
#pragma unroll
  for (int f = 0; f < 4; ++f) {
    int rowA = wm * 64 + f * 16 + fr;
    raddr[f]  = rowA * 64 + ((fq * 16) ^ (((rowA >> 1) & 3) << 4));
    int rowB = wn * 64 + f * 16 + fr;
    rbaddr[f] = rowB * 64 + ((fq * 16) ^ (((rowB >> 1) & 3) << 4));
  }

  f32x4 acc[4][4];
  const f32x4 zero = {0.f, 0.f, 0.f, 0.f};
#pragma unroll
  for (int i = 0; i < 4; ++i)
#pragma unroll
    for (int j = 0; j < 4; ++j) acc[i][j] = zero;

  const u16* Abase = A + (size_t)m0 * Dz;
  const u16* Bbase = Wt + (size_t)n0 * Dz;

  const int NKT = Dz / 32;   // 24
#pragma unroll
  for (int c = 0; c < 2; ++c) {
    GLL16(Abase + aoff[c], (char*)As[0] + (wid * 2 + c) * 1024);
    GLL16(Bbase + aoff[c], (char*)Bs[0] + (wid * 2 + c) * 1024);
  }
  int cur = 0;

  for (int kt = 0; kt < NKT; ++kt) {
    int nx = cur + 1; if (nx == 3) nx = 0;
    if (kt + 1 < NKT) {
      int ke = (kt + 1) * 32;
#pragma unroll
      for (int c = 0; c < 2; ++c) {
        GLL16(Abase + ke + aoff[c], (char*)As[nx] + (wid * 2 + c) * 1024);
        GLL16(Bbase + ke + aoff[c], (char*)Bs[nx] + (wid * 2 + c) * 1024);
      }
      asm volatile("s_waitcnt vmcnt(4)" ::: "memory");
    } else {
      asm volatile("s_waitcnt vmcnt(0)" ::: "memory");
    }
    __builtin_amdgcn_s_barrier();
    __builtin_amdgcn_sched_barrier(0);

    bf16x8 af[4], bf[4];
#pragma unroll
    for (int f = 0; f < 4; ++f) {
      af[f] = *(const bf16x8*)((const char*)As[cur] + raddr[f]);
      bf[f] = *(const bf16x8*)((const char*)Bs[cur] + rbaddr[f]);
    }
    __builtin_amdgcn_s_setprio(1);
#pragma unroll
    for (int i = 0; i < 4; ++i)
#pragma unroll
      for (int j = 0; j < 4; ++j)
        acc[i][j] = mfma16(af[i], bf[j], acc[i][j]);
    __builtin_amdgcn_s_setprio(0);
    cur = nx;
  }

  if (mode == 2) {
    float* O = (float*)out;
#pragma unroll
    for (int i = 0; i < 4; ++i) {
      int grow = m0 + wm * 64 + i * 16 + fq * 4;
#pragma unroll
      for (int j = 0; j < 4; ++j) {
        int gcol = n0 + wn * 64 + j * 16 + fr;
        float bv = bias[gcol];
#pragma unroll
        for (int r = 0; r < 4; ++r)
          O[(size_t)(grow + r) * Dz + gcol] = acc[i][j][r] + bv;
      }
    }
  } else {
    u16* O = (u16*)out;
#pragma unroll
    for (int i = 0; i < 4; ++i) {
      int grow = m0 + wm * 64 + i * 16 + fq * 4;
#pragma unroll
      for (int j = 0; j < 4; ++j) {
        int gcol = n0 + wn * 64 + j * 16 + fr;
        float bv = bias[gcol];
        int h = gcol >> 6, dh = gcol & 63;
#pragma unroll
        for (int r = 0; r < 4; ++r) {
          int t = grow + r;
          int b = t >> 11, s = t & 2047;
          int bh = b * Hz + h;
          u16 val = f2bf((acc[i][j][r] + bv) * oscale);
          size_t idx;
          if (mode == 0) {        // Q frags
            idx = ((((size_t)bh * 128 + (s >> 4)) * 2 + (dh >> 5)) * 64
                   + ((dh >> 3) & 3) * 16 + (s & 15)) * 8 + (dh & 7);
          } else if (mode == 3) { // K frags
            idx = (((((size_t)bh * 32 + (s >> 6)) * 4 + ((s >> 4) & 3)) * 2 + (dh >> 5)) * 64
                   + ((dh >> 3) & 3) * 16 + (s & 15)) * 8 + (dh & 7);
          } else {                // mode 1: V frags
            idx = (((((size_t)bh * 32 + (s >> 6)) * 4 + (dh >> 4)) * 2 + ((s >> 5) & 1)) * 64
                   + ((s >> 3) & 3) * 16 + (dh & 15)) * 8 + (s & 7);
          }
          O[idx] = val;
        }
      }
    }
  }
}

// Q is pre-scaled by 1/sqrt(DH) * log2(e) so attention can use raw v_exp_f32 (exp2)
#define QSCALE 0.1803368801111404f   // 0.125 * 1.4426950408889634

__global__ __launch_bounds__(256, 2) void gemm_qkv(
    const u16* __restrict__ qb, const u16* __restrict__ kb, const u16* __restrict__ vb,
    const u16* __restrict__ Wqt, const u16* __restrict__ Wkt, const u16* __restrict__ Wvt,
    const float* __restrict__ bq, const float* __restrict__ bk, const float* __restrict__ bv,
    u16* __restrict__ Qf, u16* __restrict__ Kf, u16* __restrict__ Vf)
{
  __shared__ u16 As[3][128 * 32];
  __shared__ u16 Bs[3][128 * 32];
  const u16* A; const u16* W; const float* bias; u16* out; int mode; float osc;
  if (blockIdx.z == 0)      { A = qb; W = Wqt; bias = bq; out = Qf; mode = 0; osc = QSCALE; }
  else if (blockIdx.z == 1) { A = kb; W = Wkt; bias = bk; out = Kf; mode = 3; osc = 1.f; }
  else                      { A = vb; W = Wvt; bias = bv; out = Vf; mode = 1; osc = 1.f; }
  gemm_core(A, W, bias, out, mode, osc, As, Bs);
}

__global__ __launch_bounds__(256, 2) void gemm_out_k(
    const u16* __restrict__ ctx, const u16* __restrict__ Wot,
    const float* __restrict__ bo, float* __restrict__ out)
{
  __shared__ u16 As[3][128 * 32];
  __shared__ u16 Bs[3][128 * 32];
  gemm_core(ctx, Wot, bo, (void*)out, 2, 1.f, As, Bs);
}

// ---------------- flash attention, causal, paired 32-row q-tiles, BARRIER-FREE ----------------
// K/V/Q pre-formatted in MFMA-fragment order by the projection epilogues, so every
// fragment load is one fully-coalesced 1KB global_load_dwordx4 per wave (L2-hit).
// No K/V LDS, no __syncthreads: waves free-run; K prefetched one tile ahead in
// registers; V issued early, consumed after softmax (latency hidden under VALU).
// Only per-wave P round-trips through 2KB LDS (same-wave lgkmcnt).
// one 16-row group's work for one k-tile
__device__ __forceinline__ void attn_group(
    const bf16x8* aq, const bf16x8 kfr[4][2], const bf16x8 vfr[4][2],
    f32x4* o, float* m_r, float* l_r, char* Pw,
    int qbase, int kt, bool diag, int fq, int fr)
{
  const f32x4 zero = {0.f, 0.f, 0.f, 0.f};
  f32x4 s[4];
#pragma unroll
  for (int j = 0; j < 4; ++j) s[j] = zero;
  __builtin_amdgcn_s_setprio(1);
#pragma unroll
  for (int j = 0; j < 4; ++j)
#pragma unroll
    for (int kk = 0; kk < 2; ++kk)
      s[j] = mfma16(aq[kk], kfr[j][kk], s[j]);
  __builtin_amdgcn_s_setprio(0);

  if (diag) {
#pragma unroll
    for (int j = 0; j < 4; ++j) {
      int keyg = kt * 64 + j * 16 + fr;
#pragma unroll
      for (int r = 0; r < 4; ++r)
        if (keyg > qbase + fq * 4 + r) s[j][r] = -1e30f;
    }
  }

  float mt[4];
#pragma unroll
  for (int r = 0; r < 4; ++r) mt[r] = s[0][r];
#pragma unroll
  for (int j = 1; j < 4; ++j)
#pragma unroll
    for (int r = 0; r < 4; ++r) mt[r] = fmaxf(mt[r], s[j][r]);

  int nd = 0;
#pragma unroll
  for (int r = 0; r < 4; ++r) nd |= (mt[r] > m_r[r] + 8.f) ? 1 : 0;
  if (__any(nd)) {
#pragma unroll
    for (int msk = 1; msk < 16; msk <<= 1)
#pragma unroll
      for (int r = 0; r < 4; ++r) mt[r] = fmaxf(mt[r], __shfl_xor(mt[r], msk));
#pragma unroll
    for (int r = 0; r < 4; ++r) {
      float mn = fmaxf(m_r[r], mt[r]);
      float alpha = __builtin_amdgcn_exp2f(m_r[r] - mn);
      m_r[r] = mn;
      l_r[r] *= alpha;
#pragma unroll
      for (int i = 0; i < 4; ++i) o[i][r] *= alpha;
    }
  }

#pragma unroll
  for (int j = 0; j < 4; ++j) {
#pragma unroll
    for (int r = 0; r < 4; ++r) {
      float e = __builtin_amdgcn_exp2f(s[j][r] - m_r[r]);
      l_r[r] += e;
      int qr = fq * 4 + r;
      int key2 = (j * 16 + fr) * 2;
      *(u16*)(Pw + qr * 128 + (key2 ^ ((qr & 7) << 4))) = f2bf(e);
    }
  }

  __builtin_amdgcn_s_setprio(1);
#pragma unroll
  for (int kk = 0; kk < 2; ++kk) {
    int cbP = (kk * 64 + fq * 16) ^ ((fr & 7) << 4);
    bf16x8 pa = *(const bf16x8*)(Pw + fr * 128 + cbP);
#pragma unroll
    for (int fo = 0; fo < 4; ++fo)
      o[fo] = mfma16(pa, vfr[fo][kk], o[fo]);
  }
  __builtin_amdgcn_s_setprio(0);
}

__global__ __launch_bounds__(128, 2) void attn_kernel(
    const u16* __restrict__ Qf, const u16* __restrict__ Kf,
    const u16* __restrict__ Vf, u16* __restrict__ ctx)
{
  __shared__ u16 Ps[2 * 16 * 64];    // 4 KB: per-wave 2KB P tile (reused by both groups)
  const int tid = threadIdx.x, wid = tid >> 6, lane = tid & 63;
  const int fq = lane >> 4, fr = lane & 15;
  const int bh = blockIdx.x;
  const int p = blockIdx.y;            // pair index 0..31
  const int b = bh / Hz, h = bh % Hz;
  const int qb0 = p * 32 + wid * 16;                 // low q-tile rows (this wave)
  const int qb1 = (NQT2 - 1 - p) * 32 + wid * 16;    // high q-tile rows
  const int nkt = ((NQT2 - p) * 32 + 63) / 64;       // k-tiles (covers high)
  const int nlo = ((p + 1) * 32 + 63) / 64;          // low group active iterations

  const bf16x8* Qf8 = (const bf16x8*)Qf + (size_t)bh * 128 * 2 * 64;
  const bf16x8* Kf8 = (const bf16x8*)Kf + (size_t)bh * 32 * 8 * 64;
  const bf16x8* Vf8 = (const bf16x8*)Vf + (size_t)bh * 32 * 8 * 64;

  bf16x8 aq[2][2];
#pragma unroll
  for (int kk = 0; kk < 2; ++kk) {
    aq[0][kk] = Qf8[((size_t)(qb0 >> 4) * 2 + kk) * 64 + lane];
    aq[1][kk] = Qf8[((size_t)(qb1 >> 4) * 2 + kk) * 64 + lane];
  }

  const f32x4 zero = {0.f, 0.f, 0.f, 0.f};
  f32x4 o[2][4];
#pragma unroll
  for (int g = 0; g < 2; ++g)
#pragma unroll
    for (int i = 0; i < 4; ++i) o[g][i] = zero;
  float m_r[2][4], l_r[2][4];
#pragma unroll
  for (int g = 0; g < 2; ++g)
#pragma unroll
    for (int r = 0; r < 4; ++r) { m_r[g][r] = -1e30f; l_r[g][r] = 0.f; }

  char* Pw = (char*)(Ps + wid * 16 * 64);

  // preload K fragments for tile 0
  bf16x8 kfr[4][2], knx[4][2], vfr[4][2];
#pragma unroll
  for (int j = 0; j < 4; ++j)
#pragma unroll
    for (int kk = 0; kk < 2; ++kk)
      kfr[j][kk] = Kf8[(size_t)(j * 2 + kk) * 64 + lane];

  for (int kt = 0; kt < nkt; ++kt) {
    // issue V loads for kt FIRST (consumed after softmax), then K for kt+1
#pragma unroll
    for (int fo = 0; fo < 4; ++fo)
#pragma unroll
      for (int kk = 0; kk < 2; ++kk)
        vfr[fo][kk] = Vf8[((size_t)kt * 8 + fo * 2 + kk) * 64 + lane];
    if (kt + 1 < nkt) {
#pragma unroll
      for (int j = 0; j < 4; ++j)
#pragma unroll
        for (int kk = 0; kk < 2; ++kk)
          knx[j][kk] = Kf8[((size_t)(kt + 1) * 8 + j * 2 + kk) * 64 + lane];
    }

    if (kt < nlo)
      attn_group(aq[0], kfr, vfr, o[0], m_r[0], l_r[0], Pw, qb0, kt, kt == nlo - 1, fq, fr);
    attn_group(aq[1], kfr, vfr, o[1], m_r[1], l_r[1], Pw, qb1, kt, kt == nkt - 1, fq, fr);

    if (kt + 1 < nkt) {
#pragma unroll
      for (int j = 0; j < 4; ++j)
#pragma unroll
        for (int kk = 0; kk < 2; ++kk)
          kfr[j][kk] = knx[j][kk];
    }
  }

  // final l reduce (once) + normalize + write ctx [B,S,D] bf16
#pragma unroll
  for (int msk = 1; msk < 16; msk <<= 1)
#pragma unroll
    for (int g = 0; g < 2; ++g)
#pragma unroll
      for (int r = 0; r < 4; ++r) l_r[g][r] += __shfl_xor(l_r[g][r], msk);

#pragma unroll
  for (int g = 0; g < 2; ++g) {
    int qb = (g == 0) ? qb0 : qb1;
#pragma unroll
    for (int fo = 0; fo < 4; ++fo) {
      int dh = fo * 16 + fr;
#pragma unroll
      for (int r = 0; r < 4; ++r) {
        int qg = qb + fq * 4 + r;
        ctx[((size_t)b * Sz + qg) * Dz + h * DHz + dh] = f2bf(o[g][fo][r] / l_r[g][r]);
      }
    }
  }
}

// ---------------- launch ----------------
extern "C" void kernel_launch(void* const* d_in, const int* in_sizes, int n_in,
                              void* d_out, int out_size, void* d_ws, size_t ws_size,
                              hipStream_t stream) {
  const float* q  = (const float*)d_in[0];
  const float* k  = (const float*)d_in[1];
  const float* v  = (const float*)d_in[2];
  const float* Wq = (const float*)d_in[3];
  const float* bq = (const float*)d_in[4];
  const float* Wk = (const float*)d_in[5];
  const float* bk = (const float*)d_in[6];
  const float* Wv = (const float*)d_in[7];
  const float* bv = (const float*)d_in[8];
  const float* Wo = (const float*)d_in[9];
  const float* bo = (const float*)d_in[10];
  float* out = (float*)d_out;

  char* ws = (char*)d_ws;
  size_t off = 0;
  auto alloc = [&](size_t bytes) {
    void* p = ws + off;
    off += (bytes + 255) & ~(size_t)255;
    return p;
  };
  u16* qb  = (u16*)alloc((size_t)Mz * Dz * 2);
  u16* kb  = (u16*)alloc((size_t)Mz * Dz * 2);
  u16* vb  = (u16*)alloc((size_t)Mz * Dz * 2);
  u16* Wqt = (u16*)alloc((size_t)Dz * Dz * 2);
  u16* Wkt = (u16*)alloc((size_t)Dz * Dz * 2);
  u16* Wvt = (u16*)alloc((size_t)Dz * Dz * 2);
  u16* Wot = (u16*)alloc((size_t)Dz * Dz * 2);
  u16* Qf  = (u16*)alloc((size_t)Bz * Hz * Sz * DHz * 2);
  u16* Kf  = (u16*)alloc((size_t)Bz * Hz * Sz * DHz * 2);
  u16* Vf  = (u16*)alloc((size_t)Bz * Hz * Sz * DHz * 2);
  u16* ctx = (u16*)alloc((size_t)Mz * Dz * 2);

  int n8 = Mz * Dz / 8;
  int cblk = (n8 + 255) / 256;
  cvt3_kernel<<<dim3(cblk, 3), 256, 0, stream>>>(q, k, v, qb, kb, vb, n8);

  wtrans4_kernel<<<dim3(Dz / 32, Dz / 32, 4), 256, 0, stream>>>(
      Wq, Wk, Wv, Wo, Wqt, Wkt, Wvt, Wot);

  gemm_qkv<<<dim3(Mz / 128, Dz / 128, 3), 256, 0, stream>>>(
      qb, kb, vb, Wqt, Wkt, Wvt, bq, bk, bv, Qf, Kf, Vf);

  attn_kernel<<<dim3(Bz * Hz, NQT2 / 2), 128, 0, stream>>>(Qf, Kf, Vf, ctx);

  gemm_out_k<<<dim3(Mz / 128, Dz / 128), 256, 0, stream>>>(ctx, Wot, bo, out);
}